// Round 2
// baseline (4699.749 us; speedup 1.0000x reference)
//
#include <hip/hip_runtime.h>
#include <hip/hip_bf16.h>

// Problem constants
#define NB 32
#define NC 256
#define NHW 3136                 // 56*56
#define NA 25690112ull           // NB*NC*NHW elements (one NCHW tensor)

// ---------------------------------------------------------------------------
// K1: BatchNorm stats -> per-channel affine (a,b): xn = a*x + b.
// Also precomputes combined depthwise weights wcomb = 0.25*(w3+w5+w7) (7x7)
// and bias sum bsum (one block per channel, so it's free here).
// ---------------------------------------------------------------------------
__launch_bounds__(256)
__global__ void bn_stats(const float* __restrict__ x, const float* __restrict__ gamma,
                         const float* __restrict__ beta,
                         const float* __restrict__ w3, const float* __restrict__ b3,
                         const float* __restrict__ w5, const float* __restrict__ b5,
                         const float* __restrict__ w7, const float* __restrict__ b7,
                         float* __restrict__ ab, float* __restrict__ wcomb,
                         float* __restrict__ bsum)
{
    const int c = blockIdx.x;
    const int tid = threadIdx.x;

    // combined depthwise weights (all three convs weighted 0.25)
    if (tid < 49) {
        const int ty = tid / 7, tx = tid % 7;
        float wv = w7[c * 49 + tid];
        if (ty >= 1 && ty <= 5 && tx >= 1 && tx <= 5) wv += w5[c * 25 + (ty - 1) * 5 + (tx - 1)];
        if (ty >= 2 && ty <= 4 && tx >= 2 && tx <= 4) wv += w3[c * 9 + (ty - 2) * 3 + (tx - 2)];
        wcomb[c * 49 + tid] = 0.25f * wv;
    }
    if (tid == 63) bsum[c] = 0.25f * (b3[c] + b5[c] + b7[c]);

    float s = 0.f, s2 = 0.f;
    for (int b = 0; b < NB; ++b) {
        const float4* p = reinterpret_cast<const float4*>(x + ((size_t)b * NC + c) * NHW);
        for (int i = tid; i < NHW / 4; i += 256) {      // 3136/4 = 784
            const float4 v = p[i];
            s += v.x + v.y + v.z + v.w;
            s2 = fmaf(v.x, v.x, s2); s2 = fmaf(v.y, v.y, s2);
            s2 = fmaf(v.z, v.z, s2); s2 = fmaf(v.w, v.w, s2);
        }
    }
    __shared__ float r1[256], r2[256];
    r1[tid] = s; r2[tid] = s2;
    __syncthreads();
    for (int off = 128; off > 0; off >>= 1) {
        if (tid < off) { r1[tid] += r1[tid + off]; r2[tid] += r2[tid + off]; }
        __syncthreads();
    }
    if (tid == 0) {
        const float inv_n = 1.f / (float)((size_t)NB * NHW);
        const float mean = r1[0] * inv_n;
        const float var = r2[0] * inv_n - mean * mean;
        const float a = gamma[c] / sqrtf(var + 1e-5f);
        ab[c] = a;
        ab[NC + c] = beta[c] - mean * a;
    }
}

// ---------------------------------------------------------------------------
// K2/K4/K6: 1x1-conv GEMM, K=256. Out[o][n] = sum_c W[o][c]*X[c][n] + bias[o]
// 64x64 tile per block, 4x4 register tile per thread, LDS-staged operands.
// All writes are contiguous (coalesced); any window permutation happens on
// the READ side of a later kernel (scattered reads are L2/L3-absorbed).
// AFF: apply BN affine while staging; (o-tile 0) dump xn as bf16, normal layout.
// WINOUT: write output as bf16 ushort4, normal layout [b][o][hw].
// RES: add shortcut read from WINDOWED layout [b][o][j*49+p] in epilogue.
// ---------------------------------------------------------------------------
template<bool AFF, bool WINOUT, bool RES>
__launch_bounds__(256)
__global__ void gemm_k256(const float* __restrict__ X, const float* __restrict__ Wt,
                          const float* __restrict__ bias, const float* __restrict__ ab,
                          const float* __restrict__ res, float* __restrict__ outF,
                          __hip_bfloat16* __restrict__ outW,
                          __hip_bfloat16* __restrict__ xnw, int O)
{
    __shared__ float Xs[64][64];
    __shared__ float Ws[64][64];
    const int b = blockIdx.z;
    const int n0 = blockIdx.x * 64;   // 49 tiles * 64 = 3136 exact
    const int o0 = blockIdx.y * 64;
    const float* Xb = X + (size_t)b * NC * NHW;
    const int t = threadIdx.x;
    const int f4 = (t & 15) * 4;      // staging column (x4)
    const int r16 = t >> 4;           // staging row group
    const int tn = (t & 15) * 4;      // compute: n offset
    const int to = (t >> 4) * 4;      // compute: o offset

    float4 acc[4];
#pragma unroll
    for (int i = 0; i < 4; ++i) acc[i] = make_float4(0.f, 0.f, 0.f, 0.f);

    for (int kc = 0; kc < 4; ++kc) {
#pragma unroll
        for (int ps = 0; ps < 4; ++ps) {
            const int rr = r16 + ps * 16;        // 0..63
            const int c = kc * 64 + rr;          // k index
            float4 xv = *reinterpret_cast<const float4*>(Xb + (size_t)c * NHW + n0 + f4);
            if (AFF) {
                const float aa = ab[c], bb = ab[NC + c];
                xv.x = fmaf(aa, xv.x, bb); xv.y = fmaf(aa, xv.y, bb);
                xv.z = fmaf(aa, xv.z, bb); xv.w = fmaf(aa, xv.w, bb);
                if (blockIdx.y == 0) {
                    union { ushort4 u; __hip_bfloat16 h[4]; } px;
                    px.h[0] = __float2bfloat16(xv.x); px.h[1] = __float2bfloat16(xv.y);
                    px.h[2] = __float2bfloat16(xv.z); px.h[3] = __float2bfloat16(xv.w);
                    *reinterpret_cast<ushort4*>(xnw + ((size_t)(b * NC + c)) * NHW + n0 + f4) = px.u;
                }
            }
            *reinterpret_cast<float4*>(&Xs[rr][f4]) = xv;
            float4 wv = *reinterpret_cast<const float4*>(Wt + (size_t)(o0 + rr) * NC + kc * 64 + f4);
            *reinterpret_cast<float4*>(&Ws[rr][f4]) = wv;
        }
        __syncthreads();
#pragma unroll
        for (int k4 = 0; k4 < 16; ++k4) {
            float4 xr[4], wr[4];
#pragma unroll
            for (int jj = 0; jj < 4; ++jj)
                xr[jj] = *reinterpret_cast<const float4*>(&Xs[k4 * 4 + jj][tn]);
#pragma unroll
            for (int i = 0; i < 4; ++i)
                wr[i] = *reinterpret_cast<const float4*>(&Ws[to + i][k4 * 4]);
#pragma unroll
            for (int i = 0; i < 4; ++i) {
                acc[i].x = fmaf(wr[i].x, xr[0].x, acc[i].x);
                acc[i].y = fmaf(wr[i].x, xr[0].y, acc[i].y);
                acc[i].z = fmaf(wr[i].x, xr[0].z, acc[i].z);
                acc[i].w = fmaf(wr[i].x, xr[0].w, acc[i].w);
                acc[i].x = fmaf(wr[i].y, xr[1].x, acc[i].x);
                acc[i].y = fmaf(wr[i].y, xr[1].y, acc[i].y);
                acc[i].z = fmaf(wr[i].y, xr[1].z, acc[i].z);
                acc[i].w = fmaf(wr[i].y, xr[1].w, acc[i].w);
                acc[i].x = fmaf(wr[i].z, xr[2].x, acc[i].x);
                acc[i].y = fmaf(wr[i].z, xr[2].y, acc[i].y);
                acc[i].z = fmaf(wr[i].z, xr[2].z, acc[i].z);
                acc[i].w = fmaf(wr[i].z, xr[2].w, acc[i].w);
                acc[i].x = fmaf(wr[i].w, xr[3].x, acc[i].x);
                acc[i].y = fmaf(wr[i].w, xr[3].y, acc[i].y);
                acc[i].z = fmaf(wr[i].w, xr[3].z, acc[i].z);
                acc[i].w = fmaf(wr[i].w, xr[3].w, acc[i].w);
            }
        }
        __syncthreads();
    }
    // epilogue
#pragma unroll
    for (int io = 0; io < 4; ++io) {
        const int o = o0 + to + io;
        const float bs = bias[o];
        float vals[4] = {acc[io].x + bs, acc[io].y + bs, acc[io].z + bs, acc[io].w + bs};
        if (WINOUT) {
            union { ushort4 u; __hip_bfloat16 h[4]; } pk;
#pragma unroll
            for (int i = 0; i < 4; ++i) pk.h[i] = __float2bfloat16(vals[i]);
            *reinterpret_cast<ushort4*>(outW + ((size_t)((size_t)b * 768 + o)) * NHW + n0 + tn) = pk.u;
        } else {
            if (RES) {
                const float* rp = res + ((size_t)(b * NC + o)) * NHW;
#pragma unroll
                for (int i = 0; i < 4; ++i) {
                    const int n = n0 + tn + i;
                    const int h = n / 56, w = n - h * 56;
                    const int widx = ((((h & 7) << 3) | (w & 7)) * 49) + (h >> 3) * 7 + (w >> 3);
                    vals[i] += rp[widx];
                }
            }
            float* op = outF + ((size_t)b * NC + o) * NHW + n0 + tn;
            *reinterpret_cast<float4*>(op) = make_float4(vals[0], vals[1], vals[2], vals[3]);
        }
    }
}

// ---------------------------------------------------------------------------
// K3: per-(window, head) attention + combined 7x7 depthwise conv + residuals.
// Reads q/k/v/x from NORMAL-layout bf16 (scattered stride-8 reads, L2/L3
// absorbed). Writes xa in WINDOWED layout [b][c][j*49+p] (contiguous runs).
// Grid (64 windows, 8 heads, 32 batch), 256 threads.
// ---------------------------------------------------------------------------
#define DOT4(accv, sv, vv2) \
    accv = fmaf(sv.x, vv2.x, accv); accv = fmaf(sv.y, vv2.y, accv); \
    accv = fmaf(sv.z, vv2.z, accv); accv = fmaf(sv.w, vv2.w, accv);

#define QK4(areg, qc) \
    areg.x = fmaf(qc, kv.x, areg.x); areg.y = fmaf(qc, kv.y, areg.y); \
    areg.z = fmaf(qc, kv.z, areg.z); areg.w = fmaf(qc, kv.w, areg.w);

__launch_bounds__(256, 3)
__global__ void attn_win(const __hip_bfloat16* __restrict__ Q,
                         const __hip_bfloat16* __restrict__ XW,
                         const float* __restrict__ wcomb, const float* __restrict__ bsumg,
                         float* __restrict__ xa)
{
    const int j = blockIdx.x;            // window id 0..63 (j1*8+j2)
    const int nh = blockIdx.y;           // head
    const int b = blockIdx.z;
    const int j1 = j >> 3, j2 = j & 7;
    const int c0 = nh * 32;
    __shared__ float qs[32][52];         // q, later reused as x_spa
    __shared__ float ks[32][52];
    __shared__ float vs[32][52];         // v + xn residual
    __shared__ float xs[32][52];         // xn window (dw conv input)
    __shared__ float S[52][52];          // scores / probs
    __shared__ float wc[32 * 49];        // combined dw weights (from global)
    __shared__ float bsum[32];
    const int tid = threadIdx.x;

    for (int idx = tid; idx < 32 * 49; idx += 256) wc[idx] = wcomb[c0 * 49 + idx];
    if (tid < 32) bsum[tid] = bsumg[c0 + tid];
    if (tid >= 32 && tid < 128) {        // zero pad cols 49..51 of vs (PV reads full quads)
        const int k = tid - 32;
        vs[k / 3][49 + (k % 3)] = 0.f;
    }

    const size_t bq = (size_t)b * 768 * NHW;
    for (int idx = tid; idx < 32 * 49; idx += 256) {
        const int d = idx / 49, p = idx % 49;
        const int h1 = p / 7, w1 = p % 7;
        const int hw = (h1 * 8 + j1) * 56 + (w1 * 8 + j2);
        const int cq = c0 + d;
        const float xv = __bfloat162float(XW[((size_t)(b * NC + cq)) * NHW + hw]);
        xs[d][p] = xv;
        qs[d][p] = __bfloat162float(Q[bq + (size_t)cq * NHW + hw]);
        ks[d][p] = __bfloat162float(Q[bq + (size_t)(256 + cq) * NHW + hw]);
        vs[d][p] = __bfloat162float(Q[bq + (size_t)(512 + cq) * NHW + hw]) + xv;
    }
    __syncthreads();

    // S = (q^T k) * 1/sqrt(32), 4x4 tiles over (query i, key jj)
    const float sc = 0.17677669529663687f;
    for (int it = tid; it < 169; it += 256) {
        const int i0 = (it / 13) * 4, j0 = (it % 13) * 4;
        float4 a0 = make_float4(0,0,0,0), a1 = a0, a2 = a0, a3 = a0;
#pragma unroll
        for (int d = 0; d < 32; ++d) {
            const float4 qv = *reinterpret_cast<const float4*>(&qs[d][i0]);
            const float4 kv = *reinterpret_cast<const float4*>(&ks[d][j0]);
            QK4(a0, qv.x) QK4(a1, qv.y) QK4(a2, qv.z) QK4(a3, qv.w)
        }
        const float4 rows[4] = {a0, a1, a2, a3};
#pragma unroll
        for (int m = 0; m < 4; ++m) {
            if (i0 + m < 49) {
                float4 sv;
                sv.x = rows[m].x * sc;                        // j0 <= 48 always valid
                sv.y = (j0 + 1 < 49) ? rows[m].y * sc : 0.f;
                sv.z = (j0 + 2 < 49) ? rows[m].z * sc : 0.f;
                sv.w = (j0 + 3 < 49) ? rows[m].w * sc : 0.f;
                *reinterpret_cast<float4*>(&S[i0 + m][j0]) = sv;
            }
        }
    }
    __syncthreads();

    // softmax over keys: 4 lanes per query row, shfl_xor row-combine
    if (tid < 196) {
        const int r = tid >> 2, qr = tid & 3;
        const int i0q = qr * 13;
        const int i1q = (qr == 3) ? 49 : i0q + 13;
        float m = -1e30f;
        for (int i = i0q; i < i1q; ++i) m = fmaxf(m, S[r][i]);
        m = fmaxf(m, __shfl_xor(m, 1));
        m = fmaxf(m, __shfl_xor(m, 2));
        float sum = 0.f;
        for (int i = i0q; i < i1q; ++i) {
            const float e = __expf(S[r][i] - m);
            S[r][i] = e; sum += e;
        }
        sum += __shfl_xor(sum, 1);
        sum += __shfl_xor(sum, 2);
        const float inv = 1.f / sum;
        for (int i = i0q; i < i1q; ++i) S[r][i] *= inv;
    }
    __syncthreads();

    // O = P @ V, 4p x 4d tiles; write into qs as spa[d][p] (q is dead)
    for (int it = tid; it < 104; it += 256) {
        const int p0 = (it / 8) * 4, d0 = (it % 8) * 4;
        float4 a0 = make_float4(0,0,0,0), a1 = a0, a2 = a0, a3 = a0; // a{mp}.{md}
#pragma unroll
        for (int jq = 0; jq < 13; ++jq) {
            const int jj = jq * 4;
            const float4 s0 = *reinterpret_cast<const float4*>(&S[p0 + 0][jj]);
            const float4 s1 = *reinterpret_cast<const float4*>(&S[p0 + 1][jj]);
            const float4 s2 = *reinterpret_cast<const float4*>(&S[p0 + 2][jj]);
            const float4 s3 = *reinterpret_cast<const float4*>(&S[p0 + 3][jj]);
            const float4 v0 = *reinterpret_cast<const float4*>(&vs[d0 + 0][jj]);
            const float4 v1 = *reinterpret_cast<const float4*>(&vs[d0 + 1][jj]);
            const float4 v2 = *reinterpret_cast<const float4*>(&vs[d0 + 2][jj]);
            const float4 v3 = *reinterpret_cast<const float4*>(&vs[d0 + 3][jj]);
            DOT4(a0.x, s0, v0) DOT4(a0.y, s0, v1) DOT4(a0.z, s0, v2) DOT4(a0.w, s0, v3)
            DOT4(a1.x, s1, v0) DOT4(a1.y, s1, v1) DOT4(a1.z, s1, v2) DOT4(a1.w, s1, v3)
            DOT4(a2.x, s2, v0) DOT4(a2.y, s2, v1) DOT4(a2.z, s2, v2) DOT4(a2.w, s2, v3)
            DOT4(a3.x, s3, v0) DOT4(a3.y, s3, v1) DOT4(a3.z, s3, v2) DOT4(a3.w, s3, v3)
        }
        const float4 rows[4] = {a0, a1, a2, a3};
#pragma unroll
        for (int mp = 0; mp < 4; ++mp) {
            if (p0 + mp < 49) {
                qs[d0 + 0][p0 + mp] = rows[mp].x;
                qs[d0 + 1][p0 + mp] = rows[mp].y;
                qs[d0 + 2][p0 + mp] = rows[mp].z;
                qs[d0 + 3][p0 + mp] = rows[mp].w;
            }
        }
    }
    __syncthreads();

    // combined dw conv + 0.25*spa + bsum + v residual; store WINDOWED layout
    if (tid < 224) {
        const int d = tid / 7, h1 = tid % 7;
        float accw[7];
#pragma unroll
        for (int w1 = 0; w1 < 7; ++w1) {
            const int p = h1 * 7 + w1;
            accw[w1] = fmaf(0.25f, qs[d][p], bsum[d] + vs[d][p]);
        }
#pragma unroll
        for (int dy = 0; dy < 7; ++dy) {
            const int ry = h1 + dy - 3;
            const bool rok = (ry >= 0) && (ry < 7);
            const float* rowp = &xs[d][(rok ? ry : 0) * 7];
            float xr[7];
#pragma unroll
            for (int i = 0; i < 7; ++i) xr[i] = rok ? rowp[i] : 0.f;
#pragma unroll
            for (int dx = 0; dx < 7; ++dx) {
                const float wv = wc[d * 49 + dy * 7 + dx];
#pragma unroll
                for (int w1 = 0; w1 < 7; ++w1) {
                    const int rx = w1 + dx - 3;
                    if (rx >= 0 && rx < 7) accw[w1] = fmaf(wv, xr[rx], accw[w1]);
                }
            }
        }
        float* xap = xa + ((size_t)(b * NC + c0 + d)) * NHW + j * 49 + h1 * 7;
#pragma unroll
        for (int w1 = 0; w1 < 7; ++w1) xap[w1] = accw[w1];
    }
}

// ---------------------------------------------------------------------------
// K5: 3x3 depthwise conv (conv_local) + SiLU.
// Reads T in WINDOWED layout (stencil-addressed scattered reads, cached),
// writes U in NORMAL layout (coalesced).
// ---------------------------------------------------------------------------
__launch_bounds__(256)
__global__ void dw3_silu(const float* __restrict__ T, const float* __restrict__ wloc,
                         const float* __restrict__ bloc, float* __restrict__ U)
{
    const int idx = blockIdx.x * 256 + threadIdx.x;
    const int w = idx % 56;
    const int h = (idx / 56) % 56;
    const int bc = idx / NHW;
    const int c = bc & 255;
    const float* tp = T + (size_t)bc * NHW;
    float acc = bloc[c];
#pragma unroll
    for (int dy = -1; dy <= 1; ++dy) {
        const int hh = h + dy;
        if (hh < 0 || hh >= 56) continue;
#pragma unroll
        for (int dx = -1; dx <= 1; ++dx) {
            const int ww = w + dx;
            if (ww < 0 || ww >= 56) continue;
            const int widx = ((((hh & 7) << 3) | (ww & 7)) * 49) + (hh >> 3) * 7 + (ww >> 3);
            acc = fmaf(wloc[c * 9 + (dy + 1) * 3 + (dx + 1)], tp[widx], acc);
        }
    }
    U[idx] = acc / (1.f + __expf(-acc));   // silu
}

// ---------------------------------------------------------------------------
// Launch. Workspace layout (floats):
//   [0,512)              : BN affine a[256], b[256]
//   wcomb = W+512        : 256*49 combined dw weights
//   bsum  = W+13056      : 256
//   xa    = W+13312      : NA floats, attention output in WINDOWED layout
//   R     = xa+NA        : 2*NA floats shared region:
//       phase 1: Qb bf16 3*NA (normal layout) + xn bf16 NA (normal layout)
//       phase 2: T (ffn_in out, windowed, NA fp32) + U (silu out, normal, NA fp32)
//   total = (13312 + 3*NA)*4 B ~ 308.3 MB
// ---------------------------------------------------------------------------
extern "C" void kernel_launch(void* const* d_in, const int* in_sizes, int n_in,
                              void* d_out, int out_size, void* d_ws, size_t ws_size,
                              hipStream_t stream)
{
    (void)in_sizes; (void)n_in; (void)out_size; (void)ws_size;
    const float* x    = (const float*)d_in[0];
    const float* g    = (const float*)d_in[1];
    const float* be   = (const float*)d_in[2];
    const float* qkvw = (const float*)d_in[3];
    const float* qkvb = (const float*)d_in[4];
    const float* w3   = (const float*)d_in[5];
    const float* b3   = (const float*)d_in[6];
    const float* w5   = (const float*)d_in[7];
    const float* b5   = (const float*)d_in[8];
    const float* w7   = (const float*)d_in[9];
    const float* b7   = (const float*)d_in[10];
    const float* fiw  = (const float*)d_in[11];
    const float* fib  = (const float*)d_in[12];
    const float* clw  = (const float*)d_in[13];
    const float* clb  = (const float*)d_in[14];
    const float* fow  = (const float*)d_in[15];
    const float* fob  = (const float*)d_in[16];
    float* out = (float*)d_out;

    float* W     = (float*)d_ws;
    float* ab    = W;
    float* wcomb = W + 512;
    float* bsum  = W + 13056;
    float* xa    = W + 13312;
    float* R     = xa + NA;
    __hip_bfloat16* Qb = (__hip_bfloat16*)R;            // 3*NA bf16, normal layout
    __hip_bfloat16* XW = Qb + 3 * NA;                   // NA bf16, normal layout
    float* T = R;                                       // aliases Qb (dead after K3)
    float* U = R + NA;

    bn_stats<<<dim3(256), dim3(256), 0, stream>>>(x, g, be, w3, b3, w5, b5, w7, b7,
                                                  ab, wcomb, bsum);
    gemm_k256<true, true, false><<<dim3(49, 12, NB), dim3(256), 0, stream>>>(
        x, qkvw, qkvb, ab, nullptr, nullptr, Qb, XW, 768);
    attn_win<<<dim3(64, 8, NB), dim3(256), 0, stream>>>(Qb, XW, wcomb, bsum, xa);
    gemm_k256<false, false, false><<<dim3(49, 4, NB), dim3(256), 0, stream>>>(
        xa, fiw, fib, nullptr, nullptr, T, nullptr, nullptr, 256);
    dw3_silu<<<dim3(NA / 256), dim3(256), 0, stream>>>(T, clw, clb, U);
    gemm_k256<false, false, true><<<dim3(49, 4, NB), dim3(256), 0, stream>>>(
        U, fow, fob, nullptr, xa, out, nullptr, nullptr, 256);
}

// Round 3
// 4502.850 us; speedup vs baseline: 1.0437x; 1.0437x over previous
//
#include <hip/hip_runtime.h>
#include <hip/hip_bf16.h>

// Problem constants
#define NB 32
#define NC 256
#define NHW 3136                 // 56*56
#define NA 25690112ull           // NB*NC*NHW elements (one NCHW tensor)

// Window mapping: h=h1*8+j1, w=w1*8+j2; j=j1*8+j2 (0..63), p=h1*7+w1 (0..48).
// Windowed linear index n' = j*49 + p within a (b,c) plane.

// ---------------------------------------------------------------------------
// K1: BatchNorm stats -> per-channel affine (a,b): xn = a*x + b.
// Also precomputes combined depthwise weights wcomb = 0.25*(w3+w5+w7) (7x7)
// and bias sum bsum.
// ---------------------------------------------------------------------------
__launch_bounds__(256)
__global__ void bn_stats(const float* __restrict__ x, const float* __restrict__ gamma,
                         const float* __restrict__ beta,
                         const float* __restrict__ w3, const float* __restrict__ b3,
                         const float* __restrict__ w5, const float* __restrict__ b5,
                         const float* __restrict__ w7, const float* __restrict__ b7,
                         float* __restrict__ ab, float* __restrict__ wcomb,
                         float* __restrict__ bsum)
{
    const int c = blockIdx.x;
    const int tid = threadIdx.x;

    if (tid < 49) {
        const int ty = tid / 7, tx = tid % 7;
        float wv = w7[c * 49 + tid];
        if (ty >= 1 && ty <= 5 && tx >= 1 && tx <= 5) wv += w5[c * 25 + (ty - 1) * 5 + (tx - 1)];
        if (ty >= 2 && ty <= 4 && tx >= 2 && tx <= 4) wv += w3[c * 9 + (ty - 2) * 3 + (tx - 2)];
        wcomb[c * 49 + tid] = 0.25f * wv;
    }
    if (tid == 63) bsum[c] = 0.25f * (b3[c] + b5[c] + b7[c]);

    float s = 0.f, s2 = 0.f;
    for (int b = 0; b < NB; ++b) {
        const float4* p = reinterpret_cast<const float4*>(x + ((size_t)b * NC + c) * NHW);
        for (int i = tid; i < NHW / 4; i += 256) {      // 3136/4 = 784
            const float4 v = p[i];
            s += v.x + v.y + v.z + v.w;
            s2 = fmaf(v.x, v.x, s2); s2 = fmaf(v.y, v.y, s2);
            s2 = fmaf(v.z, v.z, s2); s2 = fmaf(v.w, v.w, s2);
        }
    }
    __shared__ float r1[256], r2[256];
    r1[tid] = s; r2[tid] = s2;
    __syncthreads();
    for (int off = 128; off > 0; off >>= 1) {
        if (tid < off) { r1[tid] += r1[tid + off]; r2[tid] += r2[tid + off]; }
        __syncthreads();
    }
    if (tid == 0) {
        const float inv_n = 1.f / (float)((size_t)NB * NHW);
        const float mean = r1[0] * inv_n;
        const float var = r2[0] * inv_n - mean * mean;
        const float a = gamma[c] / sqrtf(var + 1e-5f);
        ab[c] = a;
        ab[NC + c] = beta[c] - mean * a;
    }
}

// ---------------------------------------------------------------------------
// K2/K4/K6: 1x1-conv GEMM, K=256. Out[o][n] = sum_c W[o][c]*X[c][n] + bias[o]
// 64x64 tile per block, 4x4 register tile per thread. The n-axis is a linear
// index: NORMAL hw order for K2/K6, WINDOWED n' order for K4 — GEMM is
// n-order-agnostic. All HBM accesses contiguous.
// AFF: apply BN affine while staging; (o-tile 0) dump xn bf16 normal layout.
// WINOUT: write output bf16 ushort4, normal layout.
// RES: add shortcut (same n-order as output) contiguous float4 in epilogue.
// ---------------------------------------------------------------------------
template<bool AFF, bool WINOUT, bool RES>
__launch_bounds__(256)
__global__ void gemm_k256(const float* __restrict__ X, const float* __restrict__ Wt,
                          const float* __restrict__ bias, const float* __restrict__ ab,
                          const float* __restrict__ res, float* __restrict__ outF,
                          __hip_bfloat16* __restrict__ outW,
                          __hip_bfloat16* __restrict__ xnw, int O)
{
    __shared__ float Xs[64][64];
    __shared__ float Ws[64][64];
    const int b = blockIdx.z;
    const int n0 = blockIdx.x * 64;   // 49 tiles * 64 = 3136 exact
    const int o0 = blockIdx.y * 64;
    const float* Xb = X + (size_t)b * NC * NHW;
    const int t = threadIdx.x;
    const int f4 = (t & 15) * 4;      // staging column (x4)
    const int r16 = t >> 4;           // staging row group
    const int tn = (t & 15) * 4;      // compute: n offset
    const int to = (t >> 4) * 4;      // compute: o offset

    float4 acc[4];
#pragma unroll
    for (int i = 0; i < 4; ++i) acc[i] = make_float4(0.f, 0.f, 0.f, 0.f);

    for (int kc = 0; kc < 4; ++kc) {
#pragma unroll
        for (int ps = 0; ps < 4; ++ps) {
            const int rr = r16 + ps * 16;        // 0..63
            const int c = kc * 64 + rr;          // k index
            float4 xv = *reinterpret_cast<const float4*>(Xb + (size_t)c * NHW + n0 + f4);
            if (AFF) {
                const float aa = ab[c], bb = ab[NC + c];
                xv.x = fmaf(aa, xv.x, bb); xv.y = fmaf(aa, xv.y, bb);
                xv.z = fmaf(aa, xv.z, bb); xv.w = fmaf(aa, xv.w, bb);
                if (blockIdx.y == 0) {
                    union { ushort4 u; __hip_bfloat16 h[4]; } px;
                    px.h[0] = __float2bfloat16(xv.x); px.h[1] = __float2bfloat16(xv.y);
                    px.h[2] = __float2bfloat16(xv.z); px.h[3] = __float2bfloat16(xv.w);
                    *reinterpret_cast<ushort4*>(xnw + ((size_t)(b * NC + c)) * NHW + n0 + f4) = px.u;
                }
            }
            *reinterpret_cast<float4*>(&Xs[rr][f4]) = xv;
            float4 wv = *reinterpret_cast<const float4*>(Wt + (size_t)(o0 + rr) * NC + kc * 64 + f4);
            *reinterpret_cast<float4*>(&Ws[rr][f4]) = wv;
        }
        __syncthreads();
#pragma unroll
        for (int k4 = 0; k4 < 16; ++k4) {
            float4 xr[4], wr[4];
#pragma unroll
            for (int jj = 0; jj < 4; ++jj)
                xr[jj] = *reinterpret_cast<const float4*>(&Xs[k4 * 4 + jj][tn]);
#pragma unroll
            for (int i = 0; i < 4; ++i)
                wr[i] = *reinterpret_cast<const float4*>(&Ws[to + i][k4 * 4]);
#pragma unroll
            for (int i = 0; i < 4; ++i) {
                acc[i].x = fmaf(wr[i].x, xr[0].x, acc[i].x);
                acc[i].y = fmaf(wr[i].x, xr[0].y, acc[i].y);
                acc[i].z = fmaf(wr[i].x, xr[0].z, acc[i].z);
                acc[i].w = fmaf(wr[i].x, xr[0].w, acc[i].w);
                acc[i].x = fmaf(wr[i].y, xr[1].x, acc[i].x);
                acc[i].y = fmaf(wr[i].y, xr[1].y, acc[i].y);
                acc[i].z = fmaf(wr[i].y, xr[1].z, acc[i].z);
                acc[i].w = fmaf(wr[i].y, xr[1].w, acc[i].w);
                acc[i].x = fmaf(wr[i].z, xr[2].x, acc[i].x);
                acc[i].y = fmaf(wr[i].z, xr[2].y, acc[i].y);
                acc[i].z = fmaf(wr[i].z, xr[2].z, acc[i].z);
                acc[i].w = fmaf(wr[i].z, xr[2].w, acc[i].w);
                acc[i].x = fmaf(wr[i].w, xr[3].x, acc[i].x);
                acc[i].y = fmaf(wr[i].w, xr[3].y, acc[i].y);
                acc[i].z = fmaf(wr[i].w, xr[3].z, acc[i].z);
                acc[i].w = fmaf(wr[i].w, xr[3].w, acc[i].w);
            }
        }
        __syncthreads();
    }
    // epilogue
#pragma unroll
    for (int io = 0; io < 4; ++io) {
        const int o = o0 + to + io;
        const float bs = bias[o];
        float vals[4] = {acc[io].x + bs, acc[io].y + bs, acc[io].z + bs, acc[io].w + bs};
        if (WINOUT) {
            union { ushort4 u; __hip_bfloat16 h[4]; } pk;
#pragma unroll
            for (int i = 0; i < 4; ++i) pk.h[i] = __float2bfloat16(vals[i]);
            *reinterpret_cast<ushort4*>(outW + ((size_t)((size_t)b * 768 + o)) * NHW + n0 + tn) = pk.u;
        } else {
            if (RES) {
                const float4 rv = *reinterpret_cast<const float4*>(
                    res + ((size_t)(b * NC + o)) * NHW + n0 + tn);
                vals[0] += rv.x; vals[1] += rv.y; vals[2] += rv.z; vals[3] += rv.w;
            }
            float* op = outF + ((size_t)b * NC + o) * NHW + n0 + tn;
            *reinterpret_cast<float4*>(op) = make_float4(vals[0], vals[1], vals[2], vals[3]);
        }
    }
}

// ---------------------------------------------------------------------------
// K2.5: in-place normal -> windowed permute of one (b,c) plane (bf16).
// Load whole plane to LDS (coalesced), sync, write back permuted (coalesced).
// Scatter exists only inside LDS. cg 0..767 -> Qb plane, 768..1023 -> XW plane.
// ---------------------------------------------------------------------------
__launch_bounds__(256)
__global__ void repack_win(__hip_bfloat16* __restrict__ Qb, __hip_bfloat16* __restrict__ XW)
{
    const int cg = blockIdx.x;
    const int b = blockIdx.y;
    unsigned short* plane = (unsigned short*)(
        (cg < 768) ? (Qb + ((size_t)b * 768 + cg) * NHW)
                   : (XW + ((size_t)b * 256 + (cg - 768)) * NHW));
    __shared__ unsigned short lds[3136];
    const int tid = threadIdx.x;
    const ushort4* in4 = reinterpret_cast<const ushort4*>(plane);
    for (int i = tid; i < 784; i += 256)
        reinterpret_cast<ushort4*>(lds)[i] = in4[i];
    __syncthreads();
    ushort4* out4 = reinterpret_cast<ushort4*>(plane);
    for (int i = tid; i < 784; i += 256) {
        unsigned short tmp[4];
#pragma unroll
        for (int e = 0; e < 4; ++e) {
            const int n = 4 * i + e;
            const int j = n / 49, p = n - 49 * j;
            const int h1 = p / 7, w1 = p - 7 * h1;
            tmp[e] = lds[(h1 * 8 + (j >> 3)) * 56 + w1 * 8 + (j & 7)];
        }
        ushort4 v; v.x = tmp[0]; v.y = tmp[1]; v.z = tmp[2]; v.w = tmp[3];
        out4[i] = v;
    }
}

// ---------------------------------------------------------------------------
// K3: per-(window, head) attention + combined 7x7 depthwise conv + residuals.
// Reads q/k/v/xn from WINDOWED bf16 (contiguous 98B runs). Writes xa in
// WINDOWED fp32 layout (contiguous). Grid (64 windows, 8 heads, 32 batch).
// ---------------------------------------------------------------------------
#define DOT4(accv, sv, vv2) \
    accv = fmaf(sv.x, vv2.x, accv); accv = fmaf(sv.y, vv2.y, accv); \
    accv = fmaf(sv.z, vv2.z, accv); accv = fmaf(sv.w, vv2.w, accv);

#define QK4(areg, qc) \
    areg.x = fmaf(qc, kv.x, areg.x); areg.y = fmaf(qc, kv.y, areg.y); \
    areg.z = fmaf(qc, kv.z, areg.z); areg.w = fmaf(qc, kv.w, areg.w);

__launch_bounds__(256, 3)
__global__ void attn_win(const __hip_bfloat16* __restrict__ Q,
                         const __hip_bfloat16* __restrict__ XW,
                         const float* __restrict__ wcomb, const float* __restrict__ bsumg,
                         float* __restrict__ xa)
{
    const int j = blockIdx.x;            // window id 0..63
    const int nh = blockIdx.y;           // head
    const int b = blockIdx.z;
    const int c0 = nh * 32;
    __shared__ float qs[32][52];         // q, later reused as x_spa
    __shared__ float ks[32][52];
    __shared__ float vs[32][52];         // v + xn residual
    __shared__ float xs[32][52];         // xn window (dw conv input)
    __shared__ float S[52][52];          // scores / probs
    __shared__ float wc[32 * 49];        // combined dw weights
    __shared__ float bsum[32];
    const int tid = threadIdx.x;

    for (int idx = tid; idx < 32 * 49; idx += 256) wc[idx] = wcomb[c0 * 49 + idx];
    if (tid < 32) bsum[tid] = bsumg[c0 + tid];
    if (tid >= 32 && tid < 128) {        // zero pad cols 49..51 of vs
        const int k = tid - 32;
        vs[k / 3][49 + (k % 3)] = 0.f;
    }

    const size_t bq = (size_t)b * 768 * NHW;
    const int wb = j * 49;
    for (int idx = tid; idx < 32 * 49; idx += 256) {
        const int d = idx / 49, p = idx % 49;
        const int cq = c0 + d;
        const float xv = __bfloat162float(XW[((size_t)(b * NC + cq)) * NHW + wb + p]);
        xs[d][p] = xv;
        qs[d][p] = __bfloat162float(Q[bq + (size_t)cq * NHW + wb + p]);
        ks[d][p] = __bfloat162float(Q[bq + (size_t)(256 + cq) * NHW + wb + p]);
        vs[d][p] = __bfloat162float(Q[bq + (size_t)(512 + cq) * NHW + wb + p]) + xv;
    }
    __syncthreads();

    // S = (q^T k) * 1/sqrt(32), 4x4 tiles
    const float sc = 0.17677669529663687f;
    for (int it = tid; it < 169; it += 256) {
        const int i0 = (it / 13) * 4, j0 = (it % 13) * 4;
        float4 a0 = make_float4(0,0,0,0), a1 = a0, a2 = a0, a3 = a0;
#pragma unroll
        for (int d = 0; d < 32; ++d) {
            const float4 qv = *reinterpret_cast<const float4*>(&qs[d][i0]);
            const float4 kv = *reinterpret_cast<const float4*>(&ks[d][j0]);
            QK4(a0, qv.x) QK4(a1, qv.y) QK4(a2, qv.z) QK4(a3, qv.w)
        }
        const float4 rows[4] = {a0, a1, a2, a3};
#pragma unroll
        for (int m = 0; m < 4; ++m) {
            if (i0 + m < 49) {
                float4 sv;
                sv.x = rows[m].x * sc;
                sv.y = (j0 + 1 < 49) ? rows[m].y * sc : 0.f;
                sv.z = (j0 + 2 < 49) ? rows[m].z * sc : 0.f;
                sv.w = (j0 + 3 < 49) ? rows[m].w * sc : 0.f;
                *reinterpret_cast<float4*>(&S[i0 + m][j0]) = sv;
            }
        }
    }
    __syncthreads();

    // softmax over keys: 4 lanes per query row, shfl_xor row-combine
    if (tid < 196) {
        const int r = tid >> 2, qr = tid & 3;
        const int i0q = qr * 13;
        const int i1q = (qr == 3) ? 49 : i0q + 13;
        float m = -1e30f;
        for (int i = i0q; i < i1q; ++i) m = fmaxf(m, S[r][i]);
        m = fmaxf(m, __shfl_xor(m, 1));
        m = fmaxf(m, __shfl_xor(m, 2));
        float sum = 0.f;
        for (int i = i0q; i < i1q; ++i) {
            const float e = __expf(S[r][i] - m);
            S[r][i] = e; sum += e;
        }
        sum += __shfl_xor(sum, 1);
        sum += __shfl_xor(sum, 2);
        const float inv = 1.f / sum;
        for (int i = i0q; i < i1q; ++i) S[r][i] *= inv;
    }
    __syncthreads();

    // O = P @ V, 4p x 4d tiles; write into qs as spa[d][p]
    for (int it = tid; it < 104; it += 256) {
        const int p0 = (it / 8) * 4, d0 = (it % 8) * 4;
        float4 a0 = make_float4(0,0,0,0), a1 = a0, a2 = a0, a3 = a0;
#pragma unroll
        for (int jq = 0; jq < 13; ++jq) {
            const int jj = jq * 4;
            const float4 s0 = *reinterpret_cast<const float4*>(&S[p0 + 0][jj]);
            const float4 s1 = *reinterpret_cast<const float4*>(&S[p0 + 1][jj]);
            const float4 s2 = *reinterpret_cast<const float4*>(&S[p0 + 2][jj]);
            const float4 s3 = *reinterpret_cast<const float4*>(&S[p0 + 3][jj]);
            const float4 v0 = *reinterpret_cast<const float4*>(&vs[d0 + 0][jj]);
            const float4 v1 = *reinterpret_cast<const float4*>(&vs[d0 + 1][jj]);
            const float4 v2 = *reinterpret_cast<const float4*>(&vs[d0 + 2][jj]);
            const float4 v3 = *reinterpret_cast<const float4*>(&vs[d0 + 3][jj]);
            DOT4(a0.x, s0, v0) DOT4(a0.y, s0, v1) DOT4(a0.z, s0, v2) DOT4(a0.w, s0, v3)
            DOT4(a1.x, s1, v0) DOT4(a1.y, s1, v1) DOT4(a1.z, s1, v2) DOT4(a1.w, s1, v3)
            DOT4(a2.x, s2, v0) DOT4(a2.y, s2, v1) DOT4(a2.z, s2, v2) DOT4(a2.w, s2, v3)
            DOT4(a3.x, s3, v0) DOT4(a3.y, s3, v1) DOT4(a3.z, s3, v2) DOT4(a3.w, s3, v3)
        }
        const float4 rows[4] = {a0, a1, a2, a3};
#pragma unroll
        for (int mp = 0; mp < 4; ++mp) {
            if (p0 + mp < 49) {
                qs[d0 + 0][p0 + mp] = rows[mp].x;
                qs[d0 + 1][p0 + mp] = rows[mp].y;
                qs[d0 + 2][p0 + mp] = rows[mp].z;
                qs[d0 + 3][p0 + mp] = rows[mp].w;
            }
        }
    }
    __syncthreads();

    // combined dw conv + 0.25*spa + bsum + v residual; store WINDOWED layout
    if (tid < 224) {
        const int d = tid / 7, h1 = tid % 7;
        float accw[7];
#pragma unroll
        for (int w1 = 0; w1 < 7; ++w1) {
            const int p = h1 * 7 + w1;
            accw[w1] = fmaf(0.25f, qs[d][p], bsum[d] + vs[d][p]);
        }
#pragma unroll
        for (int dy = 0; dy < 7; ++dy) {
            const int ry = h1 + dy - 3;
            const bool rok = (ry >= 0) && (ry < 7);
            const float* rowp = &xs[d][(rok ? ry : 0) * 7];
            float xr[7];
#pragma unroll
            for (int i = 0; i < 7; ++i) xr[i] = rok ? rowp[i] : 0.f;
#pragma unroll
            for (int dx = 0; dx < 7; ++dx) {
                const float wv = wc[d * 49 + dy * 7 + dx];
#pragma unroll
                for (int w1 = 0; w1 < 7; ++w1) {
                    const int rx = w1 + dx - 3;
                    if (rx >= 0 && rx < 7) accw[w1] = fmaf(wv, xr[rx], accw[w1]);
                }
            }
        }
        float* xap = xa + ((size_t)(b * NC + c0 + d)) * NHW + wb + h1 * 7;
#pragma unroll
        for (int w1 = 0; w1 < 7; ++w1) xap[w1] = accw[w1];
    }
}

// ---------------------------------------------------------------------------
// K5: per-(b,c)-plane: 3x3 depthwise conv (conv_local) + SiLU on T
// (windowed -> LDS-normal -> stencil -> U normal), and in-place
// windowed->normal permute of xa (shortcut for the final GEMM).
// All HBM accesses coalesced; scatter only in LDS.
// ---------------------------------------------------------------------------
__launch_bounds__(256)
__global__ void dw3_silu(const float* __restrict__ T, const float* __restrict__ wloc,
                         const float* __restrict__ bloc, float* __restrict__ U,
                         float* xa)
{
    const int c = blockIdx.x, b = blockIdx.y;
    const size_t pb = ((size_t)b * NC + c) * NHW;
    __shared__ float pl[56 * 57];        // T, normal order, stride-57 rows
    __shared__ float xpl[3136];          // xa, normal order
    const int tid = threadIdx.x;
    const float4* t4 = reinterpret_cast<const float4*>(T + pb);
    const float4* x4 = reinterpret_cast<const float4*>(xa + pb);
    for (int i = tid; i < 784; i += 256) {
        const float4 tv = t4[i];
        const float4 xv = x4[i];
        const float tt[4] = {tv.x, tv.y, tv.z, tv.w};
        const float xx[4] = {xv.x, xv.y, xv.z, xv.w};
#pragma unroll
        for (int e = 0; e < 4; ++e) {
            const int n = 4 * i + e;
            const int j = n / 49, p = n - 49 * j;
            const int h1 = p / 7, w1 = p - 7 * h1;
            const int h = h1 * 8 + (j >> 3), w = w1 * 8 + (j & 7);
            pl[h * 57 + w] = tt[e];
            xpl[h * 56 + w] = xx[e];
        }
    }
    __syncthreads();

    float wk[9];
#pragma unroll
    for (int k = 0; k < 9; ++k) wk[k] = wloc[c * 9 + k];
    const float bs = bloc[c];
    for (int i = tid; i < NHW; i += 256) {
        const int h = i / 56, w = i - 56 * h;
        float acc = bs;
#pragma unroll
        for (int dy = -1; dy <= 1; ++dy) {
            const int hh = h + dy;
            if (hh < 0 || hh >= 56) continue;
#pragma unroll
            for (int dx = -1; dx <= 1; ++dx) {
                const int ww = w + dx;
                if (ww < 0 || ww >= 56) continue;
                acc = fmaf(wk[(dy + 1) * 3 + (dx + 1)], pl[hh * 57 + ww], acc);
            }
        }
        U[pb + i] = acc / (1.f + __expf(-acc));   // silu
    }

    float4* xo4 = reinterpret_cast<float4*>(xa + pb);
    for (int i = tid; i < 784; i += 256)
        xo4[i] = make_float4(xpl[4 * i], xpl[4 * i + 1], xpl[4 * i + 2], xpl[4 * i + 3]);
}

// ---------------------------------------------------------------------------
// Launch. Workspace layout (floats):
//   [0,512)              : BN affine a[256], b[256]
//   wcomb = W+512        : 256*49 combined dw weights
//   bsum  = W+13056      : 256
//   xa    = W+13312      : NA floats — windowed after K3, NORMAL after K5 (in-place)
//   R     = xa+NA        : 2*NA floats shared region:
//       phase 1: Qb bf16 3*NA + XW bf16 NA (normal, then windowed IN-PLACE by K2.5)
//       phase 2: T (windowed fp32 NA) + U (normal fp32 NA), aliasing phase 1
//   total = (13312 + 3*NA)*4 B ~ 308.3 MB
// ---------------------------------------------------------------------------
extern "C" void kernel_launch(void* const* d_in, const int* in_sizes, int n_in,
                              void* d_out, int out_size, void* d_ws, size_t ws_size,
                              hipStream_t stream)
{
    (void)in_sizes; (void)n_in; (void)out_size; (void)ws_size;
    const float* x    = (const float*)d_in[0];
    const float* g    = (const float*)d_in[1];
    const float* be   = (const float*)d_in[2];
    const float* qkvw = (const float*)d_in[3];
    const float* qkvb = (const float*)d_in[4];
    const float* w3   = (const float*)d_in[5];
    const float* b3   = (const float*)d_in[6];
    const float* w5   = (const float*)d_in[7];
    const float* b5   = (const float*)d_in[8];
    const float* w7   = (const float*)d_in[9];
    const float* b7   = (const float*)d_in[10];
    const float* fiw  = (const float*)d_in[11];
    const float* fib  = (const float*)d_in[12];
    const float* clw  = (const float*)d_in[13];
    const float* clb  = (const float*)d_in[14];
    const float* fow  = (const float*)d_in[15];
    const float* fob  = (const float*)d_in[16];
    float* out = (float*)d_out;

    float* W     = (float*)d_ws;
    float* ab    = W;
    float* wcomb = W + 512;
    float* bsum  = W + 13056;
    float* xa    = W + 13312;
    float* R     = xa + NA;
    __hip_bfloat16* Qb = (__hip_bfloat16*)R;            // 3*NA bf16
    __hip_bfloat16* XW = Qb + 3 * NA;                   // NA bf16
    float* T = R;                                       // aliases Qb (dead after K3)
    float* U = R + NA;

    bn_stats<<<dim3(256), dim3(256), 0, stream>>>(x, g, be, w3, b3, w5, b5, w7, b7,
                                                  ab, wcomb, bsum);
    gemm_k256<true, true, false><<<dim3(49, 12, NB), dim3(256), 0, stream>>>(
        x, qkvw, qkvb, ab, nullptr, nullptr, Qb, XW, 768);
    repack_win<<<dim3(1024, NB), dim3(256), 0, stream>>>(Qb, XW);
    attn_win<<<dim3(64, 8, NB), dim3(256), 0, stream>>>(Qb, XW, wcomb, bsum, xa);
    gemm_k256<false, false, false><<<dim3(49, 4, NB), dim3(256), 0, stream>>>(
        xa, fiw, fib, nullptr, nullptr, T, nullptr, nullptr, 256);
    dw3_silu<<<dim3(256, NB), dim3(256), 0, stream>>>(T, clw, clb, U, xa);
    gemm_k256<false, false, true><<<dim3(49, 4, NB), dim3(256), 0, stream>>>(
        U, fow, fob, nullptr, xa, out, nullptr, nullptr, 256);
}

// Round 4
// 2195.741 us; speedup vs baseline: 2.1404x; 2.0507x over previous
//
#include <hip/hip_runtime.h>
#include <hip/hip_bf16.h>

// Problem constants
#define NB 32
#define NC 256
#define NHW 3136                 // 56*56
#define NA 25690112ull           // NB*NC*NHW elements (one NCHW tensor)

// Window mapping: h=h1*8+j1, w=w1*8+j2; j=j1*8+j2 (0..63), p=h1*7+w1 (0..48).
// Windowed linear index n' = j*49 + p within a (b,c) plane.

// ---------------------------------------------------------------------------
// K1: BatchNorm stats -> per-channel affine (a,b): xn = a*x + b.
// Also precomputes combined depthwise weights wcomb = 0.25*(w3+w5+w7) (7x7)
// and bias sum bsum.
// ---------------------------------------------------------------------------
__launch_bounds__(256)
__global__ void bn_stats(const float* __restrict__ x, const float* __restrict__ gamma,
                         const float* __restrict__ beta,
                         const float* __restrict__ w3, const float* __restrict__ b3,
                         const float* __restrict__ w5, const float* __restrict__ b5,
                         const float* __restrict__ w7, const float* __restrict__ b7,
                         float* __restrict__ ab, float* __restrict__ wcomb,
                         float* __restrict__ bsum)
{
    const int c = blockIdx.x;
    const int tid = threadIdx.x;

    if (tid < 49) {
        const int ty = tid / 7, tx = tid % 7;
        float wv = w7[c * 49 + tid];
        if (ty >= 1 && ty <= 5 && tx >= 1 && tx <= 5) wv += w5[c * 25 + (ty - 1) * 5 + (tx - 1)];
        if (ty >= 2 && ty <= 4 && tx >= 2 && tx <= 4) wv += w3[c * 9 + (ty - 2) * 3 + (tx - 2)];
        wcomb[c * 49 + tid] = 0.25f * wv;
    }
    if (tid == 63) bsum[c] = 0.25f * (b3[c] + b5[c] + b7[c]);

    float s = 0.f, s2 = 0.f;
    for (int b = 0; b < NB; ++b) {
        const float4* p = reinterpret_cast<const float4*>(x + ((size_t)b * NC + c) * NHW);
        for (int i = tid; i < NHW / 4; i += 256) {      // 3136/4 = 784
            const float4 v = p[i];
            s += v.x + v.y + v.z + v.w;
            s2 = fmaf(v.x, v.x, s2); s2 = fmaf(v.y, v.y, s2);
            s2 = fmaf(v.z, v.z, s2); s2 = fmaf(v.w, v.w, s2);
        }
    }
    __shared__ float r1[256], r2[256];
    r1[tid] = s; r2[tid] = s2;
    __syncthreads();
    for (int off = 128; off > 0; off >>= 1) {
        if (tid < off) { r1[tid] += r1[tid + off]; r2[tid] += r2[tid + off]; }
        __syncthreads();
    }
    if (tid == 0) {
        const float inv_n = 1.f / (float)((size_t)NB * NHW);
        const float mean = r1[0] * inv_n;
        const float var = r2[0] * inv_n - mean * mean;
        const float a = gamma[c] / sqrtf(var + 1e-5f);
        ab[c] = a;
        ab[NC + c] = beta[c] - mean * a;
    }
}

// ---------------------------------------------------------------------------
// K2/K4/K6: 1x1-conv GEMM, K=256. Out[o][n] = sum_c W[o][c]*X[c][n] + bias[o]
// 64x64 tile per block, 4x4 register tile per thread. The n-axis is a linear
// index: NORMAL hw order for K2/K6, WINDOWED n' order for K4 — GEMM is
// n-order-agnostic. All HBM accesses contiguous.
// AFF: apply BN affine while staging; (o-tile 0) dump xn bf16 normal layout.
// WINOUT: write output bf16 ushort4, normal layout.
// RES: add shortcut (same n-order as output) contiguous float4 in epilogue.
// ---------------------------------------------------------------------------
template<bool AFF, bool WINOUT, bool RES>
__launch_bounds__(256)
__global__ void gemm_k256(const float* __restrict__ X, const float* __restrict__ Wt,
                          const float* __restrict__ bias, const float* __restrict__ ab,
                          const float* __restrict__ res, float* __restrict__ outF,
                          __hip_bfloat16* __restrict__ outW,
                          __hip_bfloat16* __restrict__ xnw, int O)
{
    __shared__ float Xs[64][64];
    __shared__ float Ws[64][64];
    const int b = blockIdx.z;
    const int n0 = blockIdx.x * 64;   // 49 tiles * 64 = 3136 exact
    const int o0 = blockIdx.y * 64;
    const float* Xb = X + (size_t)b * NC * NHW;
    const int t = threadIdx.x;
    const int f4 = (t & 15) * 4;      // staging column (x4)
    const int r16 = t >> 4;           // staging row group
    const int tn = (t & 15) * 4;      // compute: n offset
    const int to = (t >> 4) * 4;      // compute: o offset

    float4 acc[4];
#pragma unroll
    for (int i = 0; i < 4; ++i) acc[i] = make_float4(0.f, 0.f, 0.f, 0.f);

    for (int kc = 0; kc < 4; ++kc) {
#pragma unroll
        for (int ps = 0; ps < 4; ++ps) {
            const int rr = r16 + ps * 16;        // 0..63
            const int c = kc * 64 + rr;          // k index
            float4 xv = *reinterpret_cast<const float4*>(Xb + (size_t)c * NHW + n0 + f4);
            if (AFF) {
                const float aa = ab[c], bb = ab[NC + c];
                xv.x = fmaf(aa, xv.x, bb); xv.y = fmaf(aa, xv.y, bb);
                xv.z = fmaf(aa, xv.z, bb); xv.w = fmaf(aa, xv.w, bb);
                if (blockIdx.y == 0) {
                    union { ushort4 u; __hip_bfloat16 h[4]; } px;
                    px.h[0] = __float2bfloat16(xv.x); px.h[1] = __float2bfloat16(xv.y);
                    px.h[2] = __float2bfloat16(xv.z); px.h[3] = __float2bfloat16(xv.w);
                    *reinterpret_cast<ushort4*>(xnw + ((size_t)(b * NC + c)) * NHW + n0 + f4) = px.u;
                }
            }
            *reinterpret_cast<float4*>(&Xs[rr][f4]) = xv;
            float4 wv = *reinterpret_cast<const float4*>(Wt + (size_t)(o0 + rr) * NC + kc * 64 + f4);
            *reinterpret_cast<float4*>(&Ws[rr][f4]) = wv;
        }
        __syncthreads();
#pragma unroll
        for (int k4 = 0; k4 < 16; ++k4) {
            float4 xr[4], wr[4];
#pragma unroll
            for (int jj = 0; jj < 4; ++jj)
                xr[jj] = *reinterpret_cast<const float4*>(&Xs[k4 * 4 + jj][tn]);
#pragma unroll
            for (int i = 0; i < 4; ++i)
                wr[i] = *reinterpret_cast<const float4*>(&Ws[to + i][k4 * 4]);
#pragma unroll
            for (int i = 0; i < 4; ++i) {
                acc[i].x = fmaf(wr[i].x, xr[0].x, acc[i].x);
                acc[i].y = fmaf(wr[i].x, xr[0].y, acc[i].y);
                acc[i].z = fmaf(wr[i].x, xr[0].z, acc[i].z);
                acc[i].w = fmaf(wr[i].x, xr[0].w, acc[i].w);
                acc[i].x = fmaf(wr[i].y, xr[1].x, acc[i].x);
                acc[i].y = fmaf(wr[i].y, xr[1].y, acc[i].y);
                acc[i].z = fmaf(wr[i].y, xr[1].z, acc[i].z);
                acc[i].w = fmaf(wr[i].y, xr[1].w, acc[i].w);
                acc[i].x = fmaf(wr[i].z, xr[2].x, acc[i].x);
                acc[i].y = fmaf(wr[i].z, xr[2].y, acc[i].y);
                acc[i].z = fmaf(wr[i].z, xr[2].z, acc[i].z);
                acc[i].w = fmaf(wr[i].z, xr[2].w, acc[i].w);
                acc[i].x = fmaf(wr[i].w, xr[3].x, acc[i].x);
                acc[i].y = fmaf(wr[i].w, xr[3].y, acc[i].y);
                acc[i].z = fmaf(wr[i].w, xr[3].z, acc[i].z);
                acc[i].w = fmaf(wr[i].w, xr[3].w, acc[i].w);
            }
        }
        __syncthreads();
    }
    // epilogue
#pragma unroll
    for (int io = 0; io < 4; ++io) {
        const int o = o0 + to + io;
        const float bs = bias[o];
        float vals[4] = {acc[io].x + bs, acc[io].y + bs, acc[io].z + bs, acc[io].w + bs};
        if (WINOUT) {
            union { ushort4 u; __hip_bfloat16 h[4]; } pk;
#pragma unroll
            for (int i = 0; i < 4; ++i) pk.h[i] = __float2bfloat16(vals[i]);
            *reinterpret_cast<ushort4*>(outW + ((size_t)((size_t)b * 768 + o)) * NHW + n0 + tn) = pk.u;
        } else {
            if (RES) {
                const float4 rv = *reinterpret_cast<const float4*>(
                    res + ((size_t)(b * NC + o)) * NHW + n0 + tn);
                vals[0] += rv.x; vals[1] += rv.y; vals[2] += rv.z; vals[3] += rv.w;
            }
            float* op = outF + ((size_t)b * NC + o) * NHW + n0 + tn;
            *reinterpret_cast<float4*>(op) = make_float4(vals[0], vals[1], vals[2], vals[3]);
        }
    }
}

// ---------------------------------------------------------------------------
// K2.5: in-place normal -> windowed permute of one (b,c) plane (bf16).
// Load whole plane to LDS (coalesced), sync, write back permuted (coalesced).
// Scatter exists only inside LDS. cg 0..767 -> Qb plane, 768..1023 -> XW plane.
// ---------------------------------------------------------------------------
__launch_bounds__(256)
__global__ void repack_win(__hip_bfloat16* __restrict__ Qb, __hip_bfloat16* __restrict__ XW)
{
    const int cg = blockIdx.x;
    const int b = blockIdx.y;
    unsigned short* plane = (unsigned short*)(
        (cg < 768) ? (Qb + ((size_t)b * 768 + cg) * NHW)
                   : (XW + ((size_t)b * 256 + (cg - 768)) * NHW));
    __shared__ unsigned short lds[3136];
    const int tid = threadIdx.x;
    const ushort4* in4 = reinterpret_cast<const ushort4*>(plane);
    for (int i = tid; i < 784; i += 256)
        reinterpret_cast<ushort4*>(lds)[i] = in4[i];
    __syncthreads();
    ushort4* out4 = reinterpret_cast<ushort4*>(plane);
    for (int i = tid; i < 784; i += 256) {
        unsigned short tmp[4];
#pragma unroll
        for (int e = 0; e < 4; ++e) {
            const int n = 4 * i + e;
            const int j = n / 49, p = n - 49 * j;
            const int h1 = p / 7, w1 = p - 7 * h1;
            tmp[e] = lds[(h1 * 8 + (j >> 3)) * 56 + w1 * 8 + (j & 7)];
        }
        ushort4 v; v.x = tmp[0]; v.y = tmp[1]; v.z = tmp[2]; v.w = tmp[3];
        out4[i] = v;
    }
}

// ---------------------------------------------------------------------------
// K3: per-(window, head) attention + combined 7x7 depthwise conv + residuals.
// Reads q/k/v/xn from WINDOWED bf16 (contiguous 98B runs). Writes xa in
// WINDOWED fp32 layout (contiguous). Grid (64 windows, 8 heads, 32 batch).
// NOTE: plain __launch_bounds__(256) — the (256,3) variant capped VGPRs at 84
// and spilled per-thread arrays to scratch: 7.9 GB fetch + 4.5 GB write of
// pure spill traffic, 3x kernel slowdown (R2/R3 post-mortem). Do not re-add.
// ---------------------------------------------------------------------------
#define DOT4(accv, sv, vv2) \
    accv = fmaf(sv.x, vv2.x, accv); accv = fmaf(sv.y, vv2.y, accv); \
    accv = fmaf(sv.z, vv2.z, accv); accv = fmaf(sv.w, vv2.w, accv);

#define QK4(areg, qc) \
    areg.x = fmaf(qc, kv.x, areg.x); areg.y = fmaf(qc, kv.y, areg.y); \
    areg.z = fmaf(qc, kv.z, areg.z); areg.w = fmaf(qc, kv.w, areg.w);

__launch_bounds__(256)
__global__ void attn_win(const __hip_bfloat16* __restrict__ Q,
                         const __hip_bfloat16* __restrict__ XW,
                         const float* __restrict__ wcomb, const float* __restrict__ bsumg,
                         float* __restrict__ xa)
{
    const int j = blockIdx.x;            // window id 0..63
    const int nh = blockIdx.y;           // head
    const int b = blockIdx.z;
    const int c0 = nh * 32;
    __shared__ float qs[32][52];         // q, later reused as x_spa
    __shared__ float ks[32][52];
    __shared__ float vs[32][52];         // v + xn residual
    __shared__ float xs[32][52];         // xn window (dw conv input)
    __shared__ float S[52][52];          // scores / probs
    __shared__ float wc[32 * 49];        // combined dw weights
    __shared__ float bsum[32];
    const int tid = threadIdx.x;

    for (int idx = tid; idx < 32 * 49; idx += 256) wc[idx] = wcomb[c0 * 49 + idx];
    if (tid < 32) bsum[tid] = bsumg[c0 + tid];
    if (tid >= 32 && tid < 128) {        // zero pad cols 49..51 of vs
        const int k = tid - 32;
        vs[k / 3][49 + (k % 3)] = 0.f;
    }

    const size_t bq = (size_t)b * 768 * NHW;
    const int wb = j * 49;
    for (int idx = tid; idx < 32 * 49; idx += 256) {
        const int d = idx / 49, p = idx % 49;
        const int cq = c0 + d;
        const float xv = __bfloat162float(XW[((size_t)(b * NC + cq)) * NHW + wb + p]);
        xs[d][p] = xv;
        qs[d][p] = __bfloat162float(Q[bq + (size_t)cq * NHW + wb + p]);
        ks[d][p] = __bfloat162float(Q[bq + (size_t)(256 + cq) * NHW + wb + p]);
        vs[d][p] = __bfloat162float(Q[bq + (size_t)(512 + cq) * NHW + wb + p]) + xv;
    }
    __syncthreads();

    // S = (q^T k) * 1/sqrt(32), 4x4 tiles
    const float sc = 0.17677669529663687f;
    for (int it = tid; it < 169; it += 256) {
        const int i0 = (it / 13) * 4, j0 = (it % 13) * 4;
        float4 a0 = make_float4(0,0,0,0), a1 = a0, a2 = a0, a3 = a0;
#pragma unroll
        for (int d = 0; d < 32; ++d) {
            const float4 qv = *reinterpret_cast<const float4*>(&qs[d][i0]);
            const float4 kv = *reinterpret_cast<const float4*>(&ks[d][j0]);
            QK4(a0, qv.x) QK4(a1, qv.y) QK4(a2, qv.z) QK4(a3, qv.w)
        }
        const float4 rows[4] = {a0, a1, a2, a3};
#pragma unroll
        for (int m = 0; m < 4; ++m) {
            if (i0 + m < 49) {
                float4 sv;
                sv.x = rows[m].x * sc;
                sv.y = (j0 + 1 < 49) ? rows[m].y * sc : 0.f;
                sv.z = (j0 + 2 < 49) ? rows[m].z * sc : 0.f;
                sv.w = (j0 + 3 < 49) ? rows[m].w * sc : 0.f;
                *reinterpret_cast<float4*>(&S[i0 + m][j0]) = sv;
            }
        }
    }
    __syncthreads();

    // softmax over keys: 4 lanes per query row, shfl_xor row-combine
    if (tid < 196) {
        const int r = tid >> 2, qr = tid & 3;
        const int i0q = qr * 13;
        const int i1q = (qr == 3) ? 49 : i0q + 13;
        float m = -1e30f;
        for (int i = i0q; i < i1q; ++i) m = fmaxf(m, S[r][i]);
        m = fmaxf(m, __shfl_xor(m, 1));
        m = fmaxf(m, __shfl_xor(m, 2));
        float sum = 0.f;
        for (int i = i0q; i < i1q; ++i) {
            const float e = __expf(S[r][i] - m);
            S[r][i] = e; sum += e;
        }
        sum += __shfl_xor(sum, 1);
        sum += __shfl_xor(sum, 2);
        const float inv = 1.f / sum;
        for (int i = i0q; i < i1q; ++i) S[r][i] *= inv;
    }
    __syncthreads();

    // O = P @ V, 4p x 4d tiles; write into qs as spa[d][p]
    for (int it = tid; it < 104; it += 256) {
        const int p0 = (it / 8) * 4, d0 = (it % 8) * 4;
        float4 a0 = make_float4(0,0,0,0), a1 = a0, a2 = a0, a3 = a0;
#pragma unroll
        for (int jq = 0; jq < 13; ++jq) {
            const int jj = jq * 4;
            const float4 s0 = *reinterpret_cast<const float4*>(&S[p0 + 0][jj]);
            const float4 s1 = *reinterpret_cast<const float4*>(&S[p0 + 1][jj]);
            const float4 s2 = *reinterpret_cast<const float4*>(&S[p0 + 2][jj]);
            const float4 s3 = *reinterpret_cast<const float4*>(&S[p0 + 3][jj]);
            const float4 v0 = *reinterpret_cast<const float4*>(&vs[d0 + 0][jj]);
            const float4 v1 = *reinterpret_cast<const float4*>(&vs[d0 + 1][jj]);
            const float4 v2 = *reinterpret_cast<const float4*>(&vs[d0 + 2][jj]);
            const float4 v3 = *reinterpret_cast<const float4*>(&vs[d0 + 3][jj]);
            DOT4(a0.x, s0, v0) DOT4(a0.y, s0, v1) DOT4(a0.z, s0, v2) DOT4(a0.w, s0, v3)
            DOT4(a1.x, s1, v0) DOT4(a1.y, s1, v1) DOT4(a1.z, s1, v2) DOT4(a1.w, s1, v3)
            DOT4(a2.x, s2, v0) DOT4(a2.y, s2, v1) DOT4(a2.z, s2, v2) DOT4(a2.w, s2, v3)
            DOT4(a3.x, s3, v0) DOT4(a3.y, s3, v1) DOT4(a3.z, s3, v2) DOT4(a3.w, s3, v3)
        }
        const float4 rows[4] = {a0, a1, a2, a3};
#pragma unroll
        for (int mp = 0; mp < 4; ++mp) {
            if (p0 + mp < 49) {
                qs[d0 + 0][p0 + mp] = rows[mp].x;
                qs[d0 + 1][p0 + mp] = rows[mp].y;
                qs[d0 + 2][p0 + mp] = rows[mp].z;
                qs[d0 + 3][p0 + mp] = rows[mp].w;
            }
        }
    }
    __syncthreads();

    // combined dw conv + 0.25*spa + bsum + v residual; store WINDOWED layout
    if (tid < 224) {
        const int d = tid / 7, h1 = tid % 7;
        float accw[7];
#pragma unroll
        for (int w1 = 0; w1 < 7; ++w1) {
            const int p = h1 * 7 + w1;
            accw[w1] = fmaf(0.25f, qs[d][p], bsum[d] + vs[d][p]);
        }
#pragma unroll
        for (int dy = 0; dy < 7; ++dy) {
            const int ry = h1 + dy - 3;
            const bool rok = (ry >= 0) && (ry < 7);
            const float* rowp = &xs[d][(rok ? ry : 0) * 7];
            float xr[7];
#pragma unroll
            for (int i = 0; i < 7; ++i) xr[i] = rok ? rowp[i] : 0.f;
#pragma unroll
            for (int dx = 0; dx < 7; ++dx) {
                const float wv = wc[d * 49 + dy * 7 + dx];
#pragma unroll
                for (int w1 = 0; w1 < 7; ++w1) {
                    const int rx = w1 + dx - 3;
                    if (rx >= 0 && rx < 7) accw[w1] = fmaf(wv, xr[rx], accw[w1]);
                }
            }
        }
        float* xap = xa + ((size_t)(b * NC + c0 + d)) * NHW + wb + h1 * 7;
#pragma unroll
        for (int w1 = 0; w1 < 7; ++w1) xap[w1] = accw[w1];
    }
}

// ---------------------------------------------------------------------------
// K5: per-(b,c)-plane: 3x3 depthwise conv (conv_local) + SiLU on T
// (windowed -> LDS-normal -> stencil -> U normal), and in-place
// windowed->normal permute of xa (shortcut for the final GEMM).
// All HBM accesses coalesced; scatter only in LDS.
// ---------------------------------------------------------------------------
__launch_bounds__(256)
__global__ void dw3_silu(const float* __restrict__ T, const float* __restrict__ wloc,
                         const float* __restrict__ bloc, float* __restrict__ U,
                         float* xa)
{
    const int c = blockIdx.x, b = blockIdx.y;
    const size_t pb = ((size_t)b * NC + c) * NHW;
    __shared__ float pl[56 * 57];        // T, normal order, stride-57 rows
    __shared__ float xpl[3136];          // xa, normal order
    const int tid = threadIdx.x;
    const float4* t4 = reinterpret_cast<const float4*>(T + pb);
    const float4* x4 = reinterpret_cast<const float4*>(xa + pb);
    for (int i = tid; i < 784; i += 256) {
        const float4 tv = t4[i];
        const float4 xv = x4[i];
        const float tt[4] = {tv.x, tv.y, tv.z, tv.w};
        const float xx[4] = {xv.x, xv.y, xv.z, xv.w};
#pragma unroll
        for (int e = 0; e < 4; ++e) {
            const int n = 4 * i + e;
            const int j = n / 49, p = n - 49 * j;
            const int h1 = p / 7, w1 = p - 7 * h1;
            const int h = h1 * 8 + (j >> 3), w = w1 * 8 + (j & 7);
            pl[h * 57 + w] = tt[e];
            xpl[h * 56 + w] = xx[e];
        }
    }
    __syncthreads();

    float wk[9];
#pragma unroll
    for (int k = 0; k < 9; ++k) wk[k] = wloc[c * 9 + k];
    const float bs = bloc[c];
    for (int i = tid; i < NHW; i += 256) {
        const int h = i / 56, w = i - 56 * h;
        float acc = bs;
#pragma unroll
        for (int dy = -1; dy <= 1; ++dy) {
            const int hh = h + dy;
            if (hh < 0 || hh >= 56) continue;
#pragma unroll
            for (int dx = -1; dx <= 1; ++dx) {
                const int ww = w + dx;
                if (ww < 0 || ww >= 56) continue;
                acc = fmaf(wk[(dy + 1) * 3 + (dx + 1)], pl[hh * 57 + ww], acc);
            }
        }
        U[pb + i] = acc / (1.f + __expf(-acc));   // silu
    }

    float4* xo4 = reinterpret_cast<float4*>(xa + pb);
    for (int i = tid; i < 784; i += 256)
        xo4[i] = make_float4(xpl[4 * i], xpl[4 * i + 1], xpl[4 * i + 2], xpl[4 * i + 3]);
}

// ---------------------------------------------------------------------------
// Launch. Workspace layout (floats):
//   [0,512)              : BN affine a[256], b[256]
//   wcomb = W+512        : 256*49 combined dw weights
//   bsum  = W+13056      : 256
//   xa    = W+13312      : NA floats — windowed after K3, NORMAL after K5 (in-place)
//   R     = xa+NA        : 2*NA floats shared region:
//       phase 1: Qb bf16 3*NA + XW bf16 NA (normal, then windowed IN-PLACE by K2.5)
//       phase 2: T (windowed fp32 NA) + U (normal fp32 NA), aliasing phase 1
//   total = (13312 + 3*NA)*4 B ~ 308.3 MB
// ---------------------------------------------------------------------------
extern "C" void kernel_launch(void* const* d_in, const int* in_sizes, int n_in,
                              void* d_out, int out_size, void* d_ws, size_t ws_size,
                              hipStream_t stream)
{
    (void)in_sizes; (void)n_in; (void)out_size; (void)ws_size;
    const float* x    = (const float*)d_in[0];
    const float* g    = (const float*)d_in[1];
    const float* be   = (const float*)d_in[2];
    const float* qkvw = (const float*)d_in[3];
    const float* qkvb = (const float*)d_in[4];
    const float* w3   = (const float*)d_in[5];
    const float* b3   = (const float*)d_in[6];
    const float* w5   = (const float*)d_in[7];
    const float* b5   = (const float*)d_in[8];
    const float* w7   = (const float*)d_in[9];
    const float* b7   = (const float*)d_in[10];
    const float* fiw  = (const float*)d_in[11];
    const float* fib  = (const float*)d_in[12];
    const float* clw  = (const float*)d_in[13];
    const float* clb  = (const float*)d_in[14];
    const float* fow  = (const float*)d_in[15];
    const float* fob  = (const float*)d_in[16];
    float* out = (float*)d_out;

    float* W     = (float*)d_ws;
    float* ab    = W;
    float* wcomb = W + 512;
    float* bsum  = W + 13056;
    float* xa    = W + 13312;
    float* R     = xa + NA;
    __hip_bfloat16* Qb = (__hip_bfloat16*)R;            // 3*NA bf16
    __hip_bfloat16* XW = Qb + 3 * NA;                   // NA bf16
    float* T = R;                                       // aliases Qb (dead after K3)
    float* U = R + NA;

    bn_stats<<<dim3(256), dim3(256), 0, stream>>>(x, g, be, w3, b3, w5, b5, w7, b7,
                                                  ab, wcomb, bsum);
    gemm_k256<true, true, false><<<dim3(49, 12, NB), dim3(256), 0, stream>>>(
        x, qkvw, qkvb, ab, nullptr, nullptr, Qb, XW, 768);
    repack_win<<<dim3(1024, NB), dim3(256), 0, stream>>>(Qb, XW);
    attn_win<<<dim3(64, 8, NB), dim3(256), 0, stream>>>(Qb, XW, wcomb, bsum, xa);
    gemm_k256<false, false, false><<<dim3(49, 4, NB), dim3(256), 0, stream>>>(
        xa, fiw, fib, nullptr, nullptr, T, nullptr, nullptr, 256);
    dw3_silu<<<dim3(256, NB), dim3(256), 0, stream>>>(T, clw, clb, U, xa);
    gemm_k256<false, false, true><<<dim3(49, 4, NB), dim3(256), 0, stream>>>(
        U, fow, fob, nullptr, xa, out, nullptr, nullptr, 256);
}